// Round 6
// baseline (1051.414 us; speedup 1.0000x reference)
//
#include <hip/hip_runtime.h>
#include <stdint.h>

// AttractorDynamics: sigma = iterate(tanh(drive + (sigma @ J^T)/tau), 10)
// B=16384, M=1024, A=512, tau=0.1, sigma0=0.
// R8: design the settle kernel for the allocator's ACTUAL rule.
//  - Evidence across R3-R7: VGPR budget = 512 / (2 * waves_per_block):
//    1024thr->64, 512thr->128, 256thr->uncapped(>=164 per m97). All
//    attribute overrides ignored. So: 256-THREAD blocks get 256 VGPRs.
//  - New shape: 512 blocks x 256 thr (2 blocks/CU -> 2 waves/SIMD TLP),
//    32 rows/block, wave owns 32x128. Live set ~170-230 < 256.
//  - LDS bank fix: R3-R7's XOR swizzle was 8-way-conflicted on A-frag
//    reads (row stride 1024B bank-aligned; 4.7-9.4M conflicts measured).
//    Now: NO xor, row stride padded to 520 bf16 (1040B = 260 words == 4
//    mod 32) -> consecutive rows rotate banks -> 2-way (free).
//  - sigma double-buffered (2x33.3KB); one barrier per step. J (hi/lo,
//    1MB, L2-resident) loaded straight to B-frags: SGPR base + 32-bit
//    voffset + kb*64B immediate. drive re-read from global per epilogue.
// drive_kernel / split_kernel unchanged.

#define B_DIM 16384
#define M_DIM 1024
#define A_DIM 512

#define SROWS 32
#define SRS 520  // padded sigma row stride in bf16 elems (1040 B)

typedef short bf16x8 __attribute__((ext_vector_type(8)));
typedef float f32x4 __attribute__((ext_vector_type(4)));

__device__ __forceinline__ unsigned short f2bf(float f) {
  unsigned int u = __float_as_uint(f);
  unsigned int r = (u + 0x7FFFu + ((u >> 16) & 1u)) >> 16;  // RNE
  return (unsigned short)r;
}
__device__ __forceinline__ float bf2f(unsigned short s) {
  return __uint_as_float(((unsigned int)s) << 16);
}
__device__ __forceinline__ float fast_tanh(float x) {
  float t = __expf(2.0f * x);
  return fmaf(-2.0f, __builtin_amdgcn_rcpf(t + 1.0f), 1.0f);
}

// ---- prep: split fp32 -> bf16 hi + bf16 lo (optionally pre-scaled) ----
__global__ void split_kernel(const float* __restrict__ src,
                             unsigned short* __restrict__ hi,
                             unsigned short* __restrict__ lo,
                             int n, float scale) {
  int i = blockIdx.x * 256 + threadIdx.x;
  if (i < n) {
    float v = src[i] * scale;
    unsigned short h = f2bf(v);
    hi[i] = h;
    lo[i] = f2bf(v - bf2f(h));
  }
}

// ---- drive GEMM: drive = x@W^T + b (fp32 out) ----
__global__ __launch_bounds__(256) void drive_kernel(
    const float* __restrict__ x, const unsigned short* __restrict__ Whi,
    const unsigned short* __restrict__ Wlo, const float* __restrict__ bias,
    float* __restrict__ drive) {
  __shared__ __align__(16) unsigned short Ah[128][40];
  __shared__ __align__(16) unsigned short Al[128][40];
  __shared__ __align__(16) unsigned short Bh[128][40];
  __shared__ __align__(16) unsigned short Bl[128][40];

  const int t = threadIdx.x;
  const int bm = blockIdx.y, bn = blockIdx.x;
  const int row = t >> 1, half = t & 1;
  const int lane = t & 63, wave = t >> 6;
  const int wm = wave >> 1, wn = wave & 1;
  const int quad = lane >> 4, l16 = lane & 15;

  f32x4 acc[4][4] = {};

  const float* xp = x + (size_t)(bm * 128 + row) * M_DIM + half * 16;
  const unsigned short* wh = Whi + (size_t)(bn * 128 + row) * M_DIM + half * 16;
  const unsigned short* wl = Wlo + (size_t)(bn * 128 + row) * M_DIM + half * 16;

  for (int k0 = 0; k0 < M_DIM; k0 += 32) {
    float4 v[4];
#pragma unroll
    for (int q = 0; q < 4; ++q) v[q] = *(const float4*)(xp + k0 + 4 * q);
    unsigned short hiv[16], lov[16];
#pragma unroll
    for (int q = 0; q < 4; ++q) {
      float fv[4] = {v[q].x, v[q].y, v[q].z, v[q].w};
#pragma unroll
      for (int e = 0; e < 4; ++e) {
        unsigned short h = f2bf(fv[e]);
        hiv[4 * q + e] = h;
        lov[4 * q + e] = f2bf(fv[e] - bf2f(h));
      }
    }
    *(uint4*)&Ah[row][half * 16]     = *(uint4*)&hiv[0];
    *(uint4*)&Ah[row][half * 16 + 8] = *(uint4*)&hiv[8];
    *(uint4*)&Al[row][half * 16]     = *(uint4*)&lov[0];
    *(uint4*)&Al[row][half * 16 + 8] = *(uint4*)&lov[8];
    *(uint4*)&Bh[row][half * 16]     = *(const uint4*)(wh + k0);
    *(uint4*)&Bh[row][half * 16 + 8] = *(const uint4*)(wh + k0 + 8);
    *(uint4*)&Bl[row][half * 16]     = *(const uint4*)(wl + k0);
    *(uint4*)&Bl[row][half * 16 + 8] = *(const uint4*)(wl + k0 + 8);
    __syncthreads();

    bf16x8 ah[4], al[4], bh[4], bl[4];
#pragma unroll
    for (int i = 0; i < 4; ++i) {
      ah[i] = *(const bf16x8*)&Ah[wm * 64 + i * 16 + l16][quad * 8];
      al[i] = *(const bf16x8*)&Al[wm * 64 + i * 16 + l16][quad * 8];
    }
#pragma unroll
    for (int j = 0; j < 4; ++j) {
      bh[j] = *(const bf16x8*)&Bh[wn * 64 + j * 16 + l16][quad * 8];
      bl[j] = *(const bf16x8*)&Bl[wn * 64 + j * 16 + l16][quad * 8];
    }
#pragma unroll
    for (int i = 0; i < 4; ++i)
#pragma unroll
      for (int j = 0; j < 4; ++j) {
        acc[i][j] = __builtin_amdgcn_mfma_f32_16x16x32_bf16(ah[i], bh[j], acc[i][j], 0, 0, 0);
        acc[i][j] = __builtin_amdgcn_mfma_f32_16x16x32_bf16(ah[i], bl[j], acc[i][j], 0, 0, 0);
        acc[i][j] = __builtin_amdgcn_mfma_f32_16x16x32_bf16(al[i], bh[j], acc[i][j], 0, 0, 0);
      }
    __syncthreads();
  }

#pragma unroll
  for (int i = 0; i < 4; ++i)
#pragma unroll
    for (int j = 0; j < 4; ++j) {
      int gcol = bn * 128 + wn * 64 + j * 16 + l16;
      float bv = bias[gcol];
#pragma unroll
      for (int r = 0; r < 4; ++r) {
        int grow = bm * 128 + wm * 64 + i * 16 + quad * 4 + r;
        drive[(size_t)grow * A_DIM + gcol] = acc[i][j][r] + bv;
      }
    }
}

// ---- fused settling loop: 9 recurrent steps, sigma LDS-resident ----
// Block: 32 rows, 256 threads (4 waves). Wave w owns cols [w*128, +128).
// sigma: two ping-pong LDS buffers, padded row stride SRS=520 bf16 ->
// conflict-free ds_read_b128 A-frags without any swizzle. One barrier/step.
// J hi/lo (1MB, L2-resident) read per-lane into B-fragments: SGPR base +
// 32-bit voffset vo[j] + imm kb*64B. drive re-read from global in epilogue.
__global__ __launch_bounds__(256) void settle_kernel(
    const unsigned short* __restrict__ Jhi,
    const unsigned short* __restrict__ Jlo,
    const float* __restrict__ drive, float* __restrict__ outf) {
  __shared__ __align__(16) unsigned short smem[2][SROWS * SRS];  // 66,560 B

  const int t = threadIdx.x;
  const int lane = t & 63, w = t >> 6;  // w in 0..3
  const int quad = lane >> 4, l16 = lane & 15;
  const int r0 = blockIdx.x * SROWS;

  // prologue: sigma1 = tanh(drive) -> buffer 0
#pragma unroll
  for (int i = 0; i < 2; ++i)
#pragma unroll
    for (int rr = 0; rr < 4; ++rr) {
      const int r = i * 16 + quad * 4 + rr;
#pragma unroll
      for (int j = 0; j < 8; ++j) {
        const int c = w * 128 + j * 16 + l16;
        smem[0][r * SRS + c] =
            f2bf(fast_tanh(drive[(size_t)(r0 + r) * A_DIM + c]));
      }
    }

  // per-lane J row byte-offsets (32-bit) against Jhi/Jlo SGPR bases
  unsigned vo[8];
#pragma unroll
  for (int j = 0; j < 8; ++j)
    vo[j] = (unsigned)(((w * 128 + j * 16 + l16) * A_DIM + quad * 8) * 2);

  // A-fragment LDS element offsets; kb adds kb*32 elems (64 B)
  int abase[2];
#pragma unroll
  for (int i = 0; i < 2; ++i) abase[i] = (i * 16 + l16) * SRS + quad * 8;

  __syncthreads();

  for (int s = 0; s < 9; ++s) {
    const unsigned short* rdb = smem[s & 1];
    unsigned short* wrb = (unsigned short*)smem[(s & 1) ^ 1];
    f32x4 acc[2][8] = {};
#pragma unroll
    for (int kb = 0; kb < 16; ++kb) {
      bf16x8 a[2], bh[8], bl[8];
      // J hi loads (vmcnt domain) + A frags (lgkmcnt domain)
#pragma unroll
      for (int j = 0; j < 8; ++j)
        bh[j] = *(const bf16x8*)((const char*)Jhi + vo[j] + kb * 64);
#pragma unroll
      for (int i = 0; i < 2; ++i)
        a[i] = *(const bf16x8*)&rdb[abase[i] + kb * 32];
#pragma unroll
      for (int i = 0; i < 2; ++i)
#pragma unroll
        for (int j = 0; j < 8; ++j)
          acc[i][j] = __builtin_amdgcn_mfma_f32_16x16x32_bf16(a[i], bh[j], acc[i][j], 0, 0, 0);
      // J lo loads issue while hi-MFMAs run; lo-MFMAs follow
#pragma unroll
      for (int j = 0; j < 8; ++j)
        bl[j] = *(const bf16x8*)((const char*)Jlo + vo[j] + kb * 64);
#pragma unroll
      for (int i = 0; i < 2; ++i)
#pragma unroll
        for (int j = 0; j < 8; ++j)
          acc[i][j] = __builtin_amdgcn_mfma_f32_16x16x32_bf16(a[i], bl[j], acc[i][j], 0, 0, 0);
    }

    if (s == 8) {  // final step: fp32 out, drive re-read from L2/HBM
#pragma unroll
      for (int i = 0; i < 2; ++i)
#pragma unroll
        for (int j = 0; j < 8; ++j) {
          const int c = w * 128 + j * 16 + l16;
          const size_t base = (size_t)(r0 + i * 16 + quad * 4) * A_DIM + c;
#pragma unroll
          for (int rr = 0; rr < 4; ++rr)
            outf[base + (size_t)rr * A_DIM] =
                fast_tanh(drive[base + (size_t)rr * A_DIM] + acc[i][j][rr]);
        }
    } else {
      // write new sigma into the IDLE buffer (no pre-write barrier needed)
#pragma unroll
      for (int i = 0; i < 2; ++i)
#pragma unroll
        for (int j = 0; j < 8; ++j) {
          const int c = w * 128 + j * 16 + l16;
#pragma unroll
          for (int rr = 0; rr < 4; ++rr) {
            const int r = i * 16 + quad * 4 + rr;
            wrb[r * SRS + c] = f2bf(fast_tanh(
                drive[(size_t)(r0 + r) * A_DIM + c] + acc[i][j][rr]));
          }
        }
      __syncthreads();  // writes visible; all waves done with old buffer
    }
  }
}

extern "C" void kernel_launch(void* const* d_in, const int* in_sizes, int n_in,
                              void* d_out, int out_size, void* d_ws, size_t ws_size,
                              hipStream_t stream) {
  const float* x = (const float*)d_in[0];
  const float* W = (const float*)d_in[1];
  const float* b = (const float*)d_in[2];
  const float* J = (const float*)d_in[3];
  float* out = (float*)d_out;

  char* ws = (char*)d_ws;
  float* drive        = (float*)(ws);                       // 33,554,432 B
  unsigned short* Whi = (unsigned short*)(ws + 33554432);   //  1,048,576 B
  unsigned short* Wlo = (unsigned short*)(ws + 34603008);   //  1,048,576 B
  unsigned short* Jhi = (unsigned short*)(ws + 35651584);   //    524,288 B
  unsigned short* Jlo = (unsigned short*)(ws + 36175872);   // end: 36,700,160

  const int nW = A_DIM * M_DIM;
  const int nJ = A_DIM * A_DIM;
  split_kernel<<<(nW + 255) / 256, 256, 0, stream>>>(W, Whi, Wlo, nW, 1.0f);
  split_kernel<<<(nJ + 255) / 256, 256, 0, stream>>>(J, Jhi, Jlo, nJ, 10.0f);

  dim3 dgrid(A_DIM / 128, B_DIM / 128);  // (4, 128)
  drive_kernel<<<dgrid, 256, 0, stream>>>(x, Whi, Wlo, b, drive);

  settle_kernel<<<B_DIM / SROWS, 256, 0, stream>>>(Jhi, Jlo, drive, out);
}

// Round 7
// 711.187 us; speedup vs baseline: 1.4784x; 1.4784x over previous
//
#include <hip/hip_runtime.h>
#include <stdint.h>

// AttractorDynamics: sigma = iterate(tanh(drive + (sigma @ J^T)/tau), 10)
// B=16384, M=1024, A=512, tau=0.1, sigma0=0.
// R9: R8 finally got the 256-VGPR budget (256-thr blocks) but still spilled:
//  - full unroll of s-loop(9) x kb-loop(16) let the scheduler hoist loads
//    across iterations -> live set > 256 -> ~365MB spill writes + re-reads,
//    plus 10x drive re-reads (320MB) thrashing J out of L2. dur==HBM-bound
//    on 2.25GB exactly.
//  - Fix: #pragma unroll 1 on BOTH loops (final step peeled out); drive
//    held in registers (dreg, 64 VGPRs) -- affordable now; everything else
//    (padded-stride LDS sigma ping-pong, 32-bit J voffsets, 1 barrier/step)
//    kept from R8. Hand-counted live set ~225 <= 256.
// drive_kernel / split_kernel unchanged.

#define B_DIM 16384
#define M_DIM 1024
#define A_DIM 512

#define SROWS 32
#define SRS 520  // padded sigma row stride in bf16 elems (1040 B)

typedef short bf16x8 __attribute__((ext_vector_type(8)));
typedef float f32x4 __attribute__((ext_vector_type(4)));

__device__ __forceinline__ unsigned short f2bf(float f) {
  unsigned int u = __float_as_uint(f);
  unsigned int r = (u + 0x7FFFu + ((u >> 16) & 1u)) >> 16;  // RNE
  return (unsigned short)r;
}
__device__ __forceinline__ float bf2f(unsigned short s) {
  return __uint_as_float(((unsigned int)s) << 16);
}
__device__ __forceinline__ float fast_tanh(float x) {
  float t = __expf(2.0f * x);
  return fmaf(-2.0f, __builtin_amdgcn_rcpf(t + 1.0f), 1.0f);
}

// ---- prep: split fp32 -> bf16 hi + bf16 lo (optionally pre-scaled) ----
__global__ void split_kernel(const float* __restrict__ src,
                             unsigned short* __restrict__ hi,
                             unsigned short* __restrict__ lo,
                             int n, float scale) {
  int i = blockIdx.x * 256 + threadIdx.x;
  if (i < n) {
    float v = src[i] * scale;
    unsigned short h = f2bf(v);
    hi[i] = h;
    lo[i] = f2bf(v - bf2f(h));
  }
}

// ---- drive GEMM: drive = x@W^T + b (fp32 out) ----
__global__ __launch_bounds__(256) void drive_kernel(
    const float* __restrict__ x, const unsigned short* __restrict__ Whi,
    const unsigned short* __restrict__ Wlo, const float* __restrict__ bias,
    float* __restrict__ drive) {
  __shared__ __align__(16) unsigned short Ah[128][40];
  __shared__ __align__(16) unsigned short Al[128][40];
  __shared__ __align__(16) unsigned short Bh[128][40];
  __shared__ __align__(16) unsigned short Bl[128][40];

  const int t = threadIdx.x;
  const int bm = blockIdx.y, bn = blockIdx.x;
  const int row = t >> 1, half = t & 1;
  const int lane = t & 63, wave = t >> 6;
  const int wm = wave >> 1, wn = wave & 1;
  const int quad = lane >> 4, l16 = lane & 15;

  f32x4 acc[4][4] = {};

  const float* xp = x + (size_t)(bm * 128 + row) * M_DIM + half * 16;
  const unsigned short* wh = Whi + (size_t)(bn * 128 + row) * M_DIM + half * 16;
  const unsigned short* wl = Wlo + (size_t)(bn * 128 + row) * M_DIM + half * 16;

  for (int k0 = 0; k0 < M_DIM; k0 += 32) {
    float4 v[4];
#pragma unroll
    for (int q = 0; q < 4; ++q) v[q] = *(const float4*)(xp + k0 + 4 * q);
    unsigned short hiv[16], lov[16];
#pragma unroll
    for (int q = 0; q < 4; ++q) {
      float fv[4] = {v[q].x, v[q].y, v[q].z, v[q].w};
#pragma unroll
      for (int e = 0; e < 4; ++e) {
        unsigned short h = f2bf(fv[e]);
        hiv[4 * q + e] = h;
        lov[4 * q + e] = f2bf(fv[e] - bf2f(h));
      }
    }
    *(uint4*)&Ah[row][half * 16]     = *(uint4*)&hiv[0];
    *(uint4*)&Ah[row][half * 16 + 8] = *(uint4*)&hiv[8];
    *(uint4*)&Al[row][half * 16]     = *(uint4*)&lov[0];
    *(uint4*)&Al[row][half * 16 + 8] = *(uint4*)&lov[8];
    *(uint4*)&Bh[row][half * 16]     = *(const uint4*)(wh + k0);
    *(uint4*)&Bh[row][half * 16 + 8] = *(const uint4*)(wh + k0 + 8);
    *(uint4*)&Bl[row][half * 16]     = *(const uint4*)(wl + k0);
    *(uint4*)&Bl[row][half * 16 + 8] = *(const uint4*)(wl + k0 + 8);
    __syncthreads();

    bf16x8 ah[4], al[4], bh[4], bl[4];
#pragma unroll
    for (int i = 0; i < 4; ++i) {
      ah[i] = *(const bf16x8*)&Ah[wm * 64 + i * 16 + l16][quad * 8];
      al[i] = *(const bf16x8*)&Al[wm * 64 + i * 16 + l16][quad * 8];
    }
#pragma unroll
    for (int j = 0; j < 4; ++j) {
      bh[j] = *(const bf16x8*)&Bh[wn * 64 + j * 16 + l16][quad * 8];
      bl[j] = *(const bf16x8*)&Bl[wn * 64 + j * 16 + l16][quad * 8];
    }
#pragma unroll
    for (int i = 0; i < 4; ++i)
#pragma unroll
      for (int j = 0; j < 4; ++j) {
        acc[i][j] = __builtin_amdgcn_mfma_f32_16x16x32_bf16(ah[i], bh[j], acc[i][j], 0, 0, 0);
        acc[i][j] = __builtin_amdgcn_mfma_f32_16x16x32_bf16(ah[i], bl[j], acc[i][j], 0, 0, 0);
        acc[i][j] = __builtin_amdgcn_mfma_f32_16x16x32_bf16(al[i], bh[j], acc[i][j], 0, 0, 0);
      }
    __syncthreads();
  }

#pragma unroll
  for (int i = 0; i < 4; ++i)
#pragma unroll
    for (int j = 0; j < 4; ++j) {
      int gcol = bn * 128 + wn * 64 + j * 16 + l16;
      float bv = bias[gcol];
#pragma unroll
      for (int r = 0; r < 4; ++r) {
        int grow = bm * 128 + wm * 64 + i * 16 + quad * 4 + r;
        drive[(size_t)grow * A_DIM + gcol] = acc[i][j][r] + bv;
      }
    }
}

// ---- fused settling loop: 9 recurrent steps, sigma LDS-resident ----
// Block: 32 rows, 256 threads (4 waves). Wave w owns cols [w*128, +128).
// sigma: two ping-pong LDS buffers, padded row stride SRS=520 bf16.
// drive: 64 fp32 in registers (dreg) loaded once. J hi/lo (1MB, L2-hot)
// loaded per-lane straight to B-frags (SGPR base + 32-bit voffset).
// #pragma unroll 1 on step & kb loops: keeps the scheduler from hoisting
// loads across iterations (R8's spill cause). Live set ~225 < 256.
#define SETTLE_KB_LOOP(RDB)                                                   \
  _Pragma("unroll 1") for (int kb = 0; kb < 16; ++kb) {                       \
    bf16x8 a[2], bh[8], bl[8];                                                \
    _Pragma("unroll") for (int j = 0; j < 8; ++j)                             \
        bh[j] = *(const bf16x8*)((const char*)Jhi + vo[j] + kb * 64);         \
    _Pragma("unroll") for (int j = 0; j < 8; ++j)                             \
        bl[j] = *(const bf16x8*)((const char*)Jlo + vo[j] + kb * 64);         \
    _Pragma("unroll") for (int i = 0; i < 2; ++i)                             \
        a[i] = *(const bf16x8*)&RDB[abase[i] + kb * 32];                      \
    _Pragma("unroll") for (int i = 0; i < 2; ++i)                             \
        _Pragma("unroll") for (int j = 0; j < 8; ++j)                         \
            acc[i][j] = __builtin_amdgcn_mfma_f32_16x16x32_bf16(              \
                a[i], bh[j], acc[i][j], 0, 0, 0);                             \
    _Pragma("unroll") for (int i = 0; i < 2; ++i)                             \
        _Pragma("unroll") for (int j = 0; j < 8; ++j)                         \
            acc[i][j] = __builtin_amdgcn_mfma_f32_16x16x32_bf16(              \
                a[i], bl[j], acc[i][j], 0, 0, 0);                             \
  }

__global__ __launch_bounds__(256) void settle_kernel(
    const unsigned short* __restrict__ Jhi,
    const unsigned short* __restrict__ Jlo,
    const float* __restrict__ drive, float* __restrict__ outf) {
  __shared__ __align__(16) unsigned short smem[2][SROWS * SRS];  // 66,560 B

  const int t = threadIdx.x;
  const int lane = t & 63, w = t >> 6;  // w in 0..3
  const int quad = lane >> 4, l16 = lane & 15;
  const int r0 = blockIdx.x * SROWS;

  // prologue: drive -> dreg (once); sigma1 = tanh(drive) -> buffer 0
  float dreg[2][8][4];
#pragma unroll
  for (int i = 0; i < 2; ++i)
#pragma unroll
    for (int j = 0; j < 8; ++j) {
      const int c = w * 128 + j * 16 + l16;
#pragma unroll
      for (int rr = 0; rr < 4; ++rr) {
        const int r = i * 16 + quad * 4 + rr;
        const float dv = drive[(size_t)(r0 + r) * A_DIM + c];
        dreg[i][j][rr] = dv;
        smem[0][r * SRS + c] = f2bf(fast_tanh(dv));
      }
    }

  // per-lane J row byte-offsets (32-bit) against Jhi/Jlo SGPR bases
  unsigned vo[8];
#pragma unroll
  for (int j = 0; j < 8; ++j)
    vo[j] = (unsigned)(((w * 128 + j * 16 + l16) * A_DIM + quad * 8) * 2);

  // A-fragment LDS element offsets; kb adds kb*32 elems (64 B)
  int abase[2];
#pragma unroll
  for (int i = 0; i < 2; ++i) abase[i] = (i * 16 + l16) * SRS + quad * 8;

  __syncthreads();

#pragma unroll 1
  for (int s = 0; s < 8; ++s) {
    const unsigned short* rdb = smem[s & 1];
    unsigned short* wrb = (unsigned short*)smem[(s & 1) ^ 1];
    f32x4 acc[2][8] = {};
    SETTLE_KB_LOOP(rdb)
    // write new sigma into the IDLE buffer (no pre-write barrier needed)
#pragma unroll
    for (int i = 0; i < 2; ++i)
#pragma unroll
      for (int j = 0; j < 8; ++j) {
        const int c = w * 128 + j * 16 + l16;
#pragma unroll
        for (int rr = 0; rr < 4; ++rr) {
          const int r = i * 16 + quad * 4 + rr;
          wrb[r * SRS + c] = f2bf(fast_tanh(dreg[i][j][rr] + acc[i][j][rr]));
        }
      }
    __syncthreads();  // writes visible; all waves done with old buffer
  }

  // final step (s=8): fp32 out from dreg + acc, no sigma rewrite
  {
    const unsigned short* rdb = smem[0];  // after 8 steps, current is buf 0
    f32x4 acc[2][8] = {};
    SETTLE_KB_LOOP(rdb)
#pragma unroll
    for (int i = 0; i < 2; ++i)
#pragma unroll
      for (int j = 0; j < 8; ++j) {
        const int c = w * 128 + j * 16 + l16;
        const size_t base = (size_t)(r0 + i * 16 + quad * 4) * A_DIM + c;
#pragma unroll
        for (int rr = 0; rr < 4; ++rr)
          outf[base + (size_t)rr * A_DIM] =
              fast_tanh(dreg[i][j][rr] + acc[i][j][rr]);
      }
  }
}

extern "C" void kernel_launch(void* const* d_in, const int* in_sizes, int n_in,
                              void* d_out, int out_size, void* d_ws, size_t ws_size,
                              hipStream_t stream) {
  const float* x = (const float*)d_in[0];
  const float* W = (const float*)d_in[1];
  const float* b = (const float*)d_in[2];
  const float* J = (const float*)d_in[3];
  float* out = (float*)d_out;

  char* ws = (char*)d_ws;
  float* drive        = (float*)(ws);                       // 33,554,432 B
  unsigned short* Whi = (unsigned short*)(ws + 33554432);   //  1,048,576 B
  unsigned short* Wlo = (unsigned short*)(ws + 34603008);   //  1,048,576 B
  unsigned short* Jhi = (unsigned short*)(ws + 35651584);   //    524,288 B
  unsigned short* Jlo = (unsigned short*)(ws + 36175872);   // end: 36,700,160

  const int nW = A_DIM * M_DIM;
  const int nJ = A_DIM * A_DIM;
  split_kernel<<<(nW + 255) / 256, 256, 0, stream>>>(W, Whi, Wlo, nW, 1.0f);
  split_kernel<<<(nJ + 255) / 256, 256, 0, stream>>>(J, Jhi, Jlo, nJ, 10.0f);

  dim3 dgrid(A_DIM / 128, B_DIM / 128);  // (4, 128)
  drive_kernel<<<dgrid, 256, 0, stream>>>(x, Whi, Wlo, b, drive);

  settle_kernel<<<B_DIM / SROWS, 256, 0, stream>>>(Jhi, Jlo, drive, out);
}

// Round 8
// 702.598 us; speedup vs baseline: 1.4965x; 1.0122x over previous
//
#include <hip/hip_runtime.h>
#include <stdint.h>

// AttractorDynamics: sigma = iterate(tanh(drive + (sigma @ J^T)/tau), 10)
// B=16384, M=1024, A=512, tau=0.1, sigma0=0.
// R10: software-pipeline the J loads (R9 was latency-bound, not BW-bound).
//  - R9 counters: spills gone (FETCH 22MB, VGPR 148) but MfmaUtil 10.8% ==
//    exactly the MFMA work fraction -> every kb iter serialized
//    {16 loads -> vmcnt(0) -> 32 MFMA} with ~300cy dead wait.
//  - Fix: 2-stage pipeline using hi/lo as the stages: prefetch lo[kb]
//    before the hi[kb] MFMA cluster, prefetch hi[kb+1] before the lo[kb]
//    cluster. ~80-160cy x 2 waves/SIMD of MFMA now covers the L2 latency.
//  - Live set: acc 64 + dreg 64 + bh 32 + bl 32 + a 8 + addr ~25 = ~225
//    <= 256 (256-thr block budget, confirmed R8/R9). unroll 1 kept on the
//    kb loop so the scheduler can't re-merge iterations (R8 spill cause).
// drive_kernel / split_kernel unchanged.

#define B_DIM 16384
#define M_DIM 1024
#define A_DIM 512

#define SROWS 32
#define SRS 520  // padded sigma row stride in bf16 elems (1040 B)

typedef short bf16x8 __attribute__((ext_vector_type(8)));
typedef float f32x4 __attribute__((ext_vector_type(4)));

__device__ __forceinline__ unsigned short f2bf(float f) {
  unsigned int u = __float_as_uint(f);
  unsigned int r = (u + 0x7FFFu + ((u >> 16) & 1u)) >> 16;  // RNE
  return (unsigned short)r;
}
__device__ __forceinline__ float bf2f(unsigned short s) {
  return __uint_as_float(((unsigned int)s) << 16);
}
__device__ __forceinline__ float fast_tanh(float x) {
  float t = __expf(2.0f * x);
  return fmaf(-2.0f, __builtin_amdgcn_rcpf(t + 1.0f), 1.0f);
}

// ---- prep: split fp32 -> bf16 hi + bf16 lo (optionally pre-scaled) ----
__global__ void split_kernel(const float* __restrict__ src,
                             unsigned short* __restrict__ hi,
                             unsigned short* __restrict__ lo,
                             int n, float scale) {
  int i = blockIdx.x * 256 + threadIdx.x;
  if (i < n) {
    float v = src[i] * scale;
    unsigned short h = f2bf(v);
    hi[i] = h;
    lo[i] = f2bf(v - bf2f(h));
  }
}

// ---- drive GEMM: drive = x@W^T + b (fp32 out) ----
__global__ __launch_bounds__(256) void drive_kernel(
    const float* __restrict__ x, const unsigned short* __restrict__ Whi,
    const unsigned short* __restrict__ Wlo, const float* __restrict__ bias,
    float* __restrict__ drive) {
  __shared__ __align__(16) unsigned short Ah[128][40];
  __shared__ __align__(16) unsigned short Al[128][40];
  __shared__ __align__(16) unsigned short Bh[128][40];
  __shared__ __align__(16) unsigned short Bl[128][40];

  const int t = threadIdx.x;
  const int bm = blockIdx.y, bn = blockIdx.x;
  const int row = t >> 1, half = t & 1;
  const int lane = t & 63, wave = t >> 6;
  const int wm = wave >> 1, wn = wave & 1;
  const int quad = lane >> 4, l16 = lane & 15;

  f32x4 acc[4][4] = {};

  const float* xp = x + (size_t)(bm * 128 + row) * M_DIM + half * 16;
  const unsigned short* wh = Whi + (size_t)(bn * 128 + row) * M_DIM + half * 16;
  const unsigned short* wl = Wlo + (size_t)(bn * 128 + row) * M_DIM + half * 16;

  for (int k0 = 0; k0 < M_DIM; k0 += 32) {
    float4 v[4];
#pragma unroll
    for (int q = 0; q < 4; ++q) v[q] = *(const float4*)(xp + k0 + 4 * q);
    unsigned short hiv[16], lov[16];
#pragma unroll
    for (int q = 0; q < 4; ++q) {
      float fv[4] = {v[q].x, v[q].y, v[q].z, v[q].w};
#pragma unroll
      for (int e = 0; e < 4; ++e) {
        unsigned short h = f2bf(fv[e]);
        hiv[4 * q + e] = h;
        lov[4 * q + e] = f2bf(fv[e] - bf2f(h));
      }
    }
    *(uint4*)&Ah[row][half * 16]     = *(uint4*)&hiv[0];
    *(uint4*)&Ah[row][half * 16 + 8] = *(uint4*)&hiv[8];
    *(uint4*)&Al[row][half * 16]     = *(uint4*)&lov[0];
    *(uint4*)&Al[row][half * 16 + 8] = *(uint4*)&lov[8];
    *(uint4*)&Bh[row][half * 16]     = *(const uint4*)(wh + k0);
    *(uint4*)&Bh[row][half * 16 + 8] = *(const uint4*)(wh + k0 + 8);
    *(uint4*)&Bl[row][half * 16]     = *(const uint4*)(wl + k0);
    *(uint4*)&Bl[row][half * 16 + 8] = *(const uint4*)(wl + k0 + 8);
    __syncthreads();

    bf16x8 ah[4], al[4], bh[4], bl[4];
#pragma unroll
    for (int i = 0; i < 4; ++i) {
      ah[i] = *(const bf16x8*)&Ah[wm * 64 + i * 16 + l16][quad * 8];
      al[i] = *(const bf16x8*)&Al[wm * 64 + i * 16 + l16][quad * 8];
    }
#pragma unroll
    for (int j = 0; j < 4; ++j) {
      bh[j] = *(const bf16x8*)&Bh[wn * 64 + j * 16 + l16][quad * 8];
      bl[j] = *(const bf16x8*)&Bl[wn * 64 + j * 16 + l16][quad * 8];
    }
#pragma unroll
    for (int i = 0; i < 4; ++i)
#pragma unroll
      for (int j = 0; j < 4; ++j) {
        acc[i][j] = __builtin_amdgcn_mfma_f32_16x16x32_bf16(ah[i], bh[j], acc[i][j], 0, 0, 0);
        acc[i][j] = __builtin_amdgcn_mfma_f32_16x16x32_bf16(ah[i], bl[j], acc[i][j], 0, 0, 0);
        acc[i][j] = __builtin_amdgcn_mfma_f32_16x16x32_bf16(al[i], bh[j], acc[i][j], 0, 0, 0);
      }
    __syncthreads();
  }

#pragma unroll
  for (int i = 0; i < 4; ++i)
#pragma unroll
    for (int j = 0; j < 4; ++j) {
      int gcol = bn * 128 + wn * 64 + j * 16 + l16;
      float bv = bias[gcol];
#pragma unroll
      for (int r = 0; r < 4; ++r) {
        int grow = bm * 128 + wm * 64 + i * 16 + quad * 4 + r;
        drive[(size_t)grow * A_DIM + gcol] = acc[i][j][r] + bv;
      }
    }
}

// ---- fused settling loop: 9 recurrent steps, sigma LDS-resident ----
// Block: 32 rows, 256 threads (4 waves, 2 blocks/CU -> 2 waves/SIMD).
// Wave w owns cols [w*128, +128). sigma: two ping-pong LDS buffers, padded
// row stride SRS=520 bf16. drive: 64 fp32 in registers. J hi/lo (1MB,
// L2-hot) loaded per-lane to B-frags; 2-STAGE PIPELINE: lo[kb] prefetched
// under hi[kb]'s MFMAs, hi[kb+1] prefetched under lo[kb]'s MFMAs.
#define SETTLE_KB_LOOP(RDB)                                                   \
  {                                                                           \
    bf16x8 bh[8], bl[8];                                                      \
    _Pragma("unroll") for (int j = 0; j < 8; ++j)                             \
        bh[j] = *(const bf16x8*)((const char*)Jhi + vo[j]);                   \
    _Pragma("unroll 1") for (int kb = 0; kb < 16; ++kb) {                     \
      bf16x8 a[2];                                                            \
      /* stage: prefetch lo[kb] (used after hi MFMAs) */                      \
      _Pragma("unroll") for (int j = 0; j < 8; ++j)                           \
          bl[j] = *(const bf16x8*)((const char*)Jlo + vo[j] + kb * 64);       \
      _Pragma("unroll") for (int i = 0; i < 2; ++i)                           \
          a[i] = *(const bf16x8*)&RDB[abase[i] + kb * 32];                    \
      _Pragma("unroll") for (int i = 0; i < 2; ++i)                           \
          _Pragma("unroll") for (int j = 0; j < 8; ++j)                       \
              acc[i][j] = __builtin_amdgcn_mfma_f32_16x16x32_bf16(            \
                  a[i], bh[j], acc[i][j], 0, 0, 0);                           \
      /* stage: prefetch hi[kb+1] (wraps harmlessly on last iter) */          \
      const int nko = ((kb + 1) & 15) * 64;                                   \
      _Pragma("unroll") for (int j = 0; j < 8; ++j)                           \
          bh[j] = *(const bf16x8*)((const char*)Jhi + vo[j] + nko);           \
      _Pragma("unroll") for (int i = 0; i < 2; ++i)                           \
          _Pragma("unroll") for (int j = 0; j < 8; ++j)                       \
              acc[i][j] = __builtin_amdgcn_mfma_f32_16x16x32_bf16(            \
                  a[i], bl[j], acc[i][j], 0, 0, 0);                           \
    }                                                                         \
  }

__global__ __launch_bounds__(256) void settle_kernel(
    const unsigned short* __restrict__ Jhi,
    const unsigned short* __restrict__ Jlo,
    const float* __restrict__ drive, float* __restrict__ outf) {
  __shared__ __align__(16) unsigned short smem[2][SROWS * SRS];  // 66,560 B

  const int t = threadIdx.x;
  const int lane = t & 63, w = t >> 6;  // w in 0..3
  const int quad = lane >> 4, l16 = lane & 15;
  const int r0 = blockIdx.x * SROWS;

  // prologue: drive -> dreg (once); sigma1 = tanh(drive) -> buffer 0
  float dreg[2][8][4];
#pragma unroll
  for (int i = 0; i < 2; ++i)
#pragma unroll
    for (int j = 0; j < 8; ++j) {
      const int c = w * 128 + j * 16 + l16;
#pragma unroll
      for (int rr = 0; rr < 4; ++rr) {
        const int r = i * 16 + quad * 4 + rr;
        const float dv = drive[(size_t)(r0 + r) * A_DIM + c];
        dreg[i][j][rr] = dv;
        smem[0][r * SRS + c] = f2bf(fast_tanh(dv));
      }
    }

  // per-lane J row byte-offsets (32-bit) against Jhi/Jlo SGPR bases
  unsigned vo[8];
#pragma unroll
  for (int j = 0; j < 8; ++j)
    vo[j] = (unsigned)(((w * 128 + j * 16 + l16) * A_DIM + quad * 8) * 2);

  // A-fragment LDS element offsets; kb adds kb*32 elems (64 B)
  int abase[2];
#pragma unroll
  for (int i = 0; i < 2; ++i) abase[i] = (i * 16 + l16) * SRS + quad * 8;

  __syncthreads();

#pragma unroll 1
  for (int s = 0; s < 8; ++s) {
    const unsigned short* rdb = smem[s & 1];
    unsigned short* wrb = (unsigned short*)smem[(s & 1) ^ 1];
    f32x4 acc[2][8] = {};
    SETTLE_KB_LOOP(rdb)
    // write new sigma into the IDLE buffer (no pre-write barrier needed)
#pragma unroll
    for (int i = 0; i < 2; ++i)
#pragma unroll
      for (int j = 0; j < 8; ++j) {
        const int c = w * 128 + j * 16 + l16;
#pragma unroll
        for (int rr = 0; rr < 4; ++rr) {
          const int r = i * 16 + quad * 4 + rr;
          wrb[r * SRS + c] = f2bf(fast_tanh(dreg[i][j][rr] + acc[i][j][rr]));
        }
      }
    __syncthreads();  // writes visible; all waves done with old buffer
  }

  // final step (s=8): fp32 out from dreg + acc, no sigma rewrite
  {
    const unsigned short* rdb = smem[0];  // after 8 steps, current is buf 0
    f32x4 acc[2][8] = {};
    SETTLE_KB_LOOP(rdb)
#pragma unroll
    for (int i = 0; i < 2; ++i)
#pragma unroll
      for (int j = 0; j < 8; ++j) {
        const int c = w * 128 + j * 16 + l16;
        const size_t base = (size_t)(r0 + i * 16 + quad * 4) * A_DIM + c;
#pragma unroll
        for (int rr = 0; rr < 4; ++rr)
          outf[base + (size_t)rr * A_DIM] =
              fast_tanh(dreg[i][j][rr] + acc[i][j][rr]);
      }
  }
}

extern "C" void kernel_launch(void* const* d_in, const int* in_sizes, int n_in,
                              void* d_out, int out_size, void* d_ws, size_t ws_size,
                              hipStream_t stream) {
  const float* x = (const float*)d_in[0];
  const float* W = (const float*)d_in[1];
  const float* b = (const float*)d_in[2];
  const float* J = (const float*)d_in[3];
  float* out = (float*)d_out;

  char* ws = (char*)d_ws;
  float* drive        = (float*)(ws);                       // 33,554,432 B
  unsigned short* Whi = (unsigned short*)(ws + 33554432);   //  1,048,576 B
  unsigned short* Wlo = (unsigned short*)(ws + 34603008);   //  1,048,576 B
  unsigned short* Jhi = (unsigned short*)(ws + 35651584);   //    524,288 B
  unsigned short* Jlo = (unsigned short*)(ws + 36175872);   // end: 36,700,160

  const int nW = A_DIM * M_DIM;
  const int nJ = A_DIM * A_DIM;
  split_kernel<<<(nW + 255) / 256, 256, 0, stream>>>(W, Whi, Wlo, nW, 1.0f);
  split_kernel<<<(nJ + 255) / 256, 256, 0, stream>>>(J, Jhi, Jlo, nJ, 10.0f);

  dim3 dgrid(A_DIM / 128, B_DIM / 128);  // (4, 128)
  drive_kernel<<<dgrid, 256, 0, stream>>>(x, Whi, Wlo, b, drive);

  settle_kernel<<<B_DIM / SROWS, 256, 0, stream>>>(Jhi, Jlo, drive, out);
}